// Round 1
// baseline (9435.421 us; speedup 1.0000x reference)
//
#include <hip/hip_runtime.h>

#define N_M 100000
#define N_D 30000
#define N_A 80000

// ---------------------------------------------------------------------------
// scatter: for each edge e, agg[dst[e]][:] += x[src[e]][:] * ew[e]
// D = feature width (64 layer1, 32 layer2). D/4 threads per edge, float4 each.
// unsafeAtomicAdd -> global_atomic_add_f32 (HW atomic, no CAS loop).
// ---------------------------------------------------------------------------
template<int D>
__global__ __launch_bounds__(256) void scatter_kernel(
    const float* __restrict__ x,
    const int* __restrict__ src,
    const int* __restrict__ dst,
    const float* __restrict__ ew,
    float* __restrict__ agg,
    int nE) {
  constexpr int PER = D / 4;
  long long gid = (long long)blockIdx.x * blockDim.x + threadIdx.x;
  int e = (int)(gid / PER);
  if (e >= nE) return;
  int c = ((int)(gid % PER)) * 4;
  int s = src[e];
  int d = dst[e];
  float w = ew[e];
  const float4 xv = *(const float4*)(x + (size_t)s * D + c);
  float* out = agg + (size_t)d * D + c;
  unsafeAtomicAdd(out + 0, xv.x * w);
  unsafeAtomicAdd(out + 1, xv.y * w);
  unsafeAtomicAdd(out + 2, xv.z * w);
  unsafeAtomicAdd(out + 3, xv.w * w);
}

// ---------------------------------------------------------------------------
// Layer-1 node update, one relation:
//   h = relu(agg @ Wrel + b + x @ Wroot), all 64x64.
// One wave per node; lane j computes output dim j. W staged in LDS.
// ---------------------------------------------------------------------------
__global__ __launch_bounds__(256) void l1_node1(
    const float* __restrict__ agg,
    const float* __restrict__ x,
    const float* __restrict__ Wrel,
    const float* __restrict__ bias,
    const float* __restrict__ Wroot,
    float* __restrict__ h, int n) {
  __shared__ float Wr[64 * 64];
  __shared__ float Wt[64 * 64];
  for (int i = threadIdx.x; i < 64 * 64; i += 256) {
    Wr[i] = Wrel[i];
    Wt[i] = Wroot[i];
  }
  __syncthreads();
  int lane = threadIdx.x & 63;
  int wave = (blockIdx.x * 256 + threadIdx.x) >> 6;
  int nWaves = gridDim.x * 4;
  float bj = bias[lane];
  for (int node = wave; node < n; node += nWaves) {
    const float* ar = agg + (size_t)node * 64;
    const float* xr = x + (size_t)node * 64;
    float acc = bj;
#pragma unroll
    for (int k = 0; k < 64; k++) {
      acc = fmaf(ar[k], Wr[k * 64 + lane], acc);
      acc = fmaf(xr[k], Wt[k * 64 + lane], acc);
    }
    h[(size_t)node * 64 + lane] = fmaxf(acc, 0.0f);
  }
}

// ---------------------------------------------------------------------------
// Layer-1 node update for movies (two incoming relations, HeteroConv sum):
//   h_m = relu(agg_dm@Wrel[1] + agg_am@Wrel[3] + x_m@(Wroot[1]+Wroot[3])
//              + b[1] + b[3])
// ---------------------------------------------------------------------------
__global__ __launch_bounds__(256) void l1_node_movie(
    const float* __restrict__ agg1,   // agg_dm (relation 1)
    const float* __restrict__ agg2,   // agg_am (relation 3)
    const float* __restrict__ x,
    const float* __restrict__ W1rel,  // base of (4,64,64)
    const float* __restrict__ b1,     // base of (4,64)
    const float* __restrict__ W1root, // base of (4,64,64)
    float* __restrict__ h, int n) {
  __shared__ float Wr1[64 * 64];
  __shared__ float Wr3[64 * 64];
  __shared__ float Wtc[64 * 64];
  for (int i = threadIdx.x; i < 64 * 64; i += 256) {
    Wr1[i] = W1rel[1 * 4096 + i];
    Wr3[i] = W1rel[3 * 4096 + i];
    Wtc[i] = W1root[1 * 4096 + i] + W1root[3 * 4096 + i];
  }
  __syncthreads();
  int lane = threadIdx.x & 63;
  int wave = (blockIdx.x * 256 + threadIdx.x) >> 6;
  int nWaves = gridDim.x * 4;
  float bj = b1[1 * 64 + lane] + b1[3 * 64 + lane];
  for (int node = wave; node < n; node += nWaves) {
    const float* a1 = agg1 + (size_t)node * 64;
    const float* a2 = agg2 + (size_t)node * 64;
    const float* xr = x + (size_t)node * 64;
    float acc = bj;
#pragma unroll
    for (int k = 0; k < 64; k++) {
      acc = fmaf(a1[k], Wr1[k * 64 + lane], acc);
      acc = fmaf(a2[k], Wr3[k * 64 + lane], acc);
      acc = fmaf(xr[k], Wtc[k * 64 + lane], acc);
    }
    h[(size_t)node * 64 + lane] = fmaxf(acc, 0.0f);
  }
}

// ---------------------------------------------------------------------------
// y = in @ W  (64 -> 32), no bias. One thread per output element.
// ---------------------------------------------------------------------------
__global__ __launch_bounds__(256) void matmul_64x32(
    const float* __restrict__ in,
    const float* __restrict__ W,   // 64x32
    float* __restrict__ out, int n) {
  __shared__ float Ws[64 * 32];
  for (int i = threadIdx.x; i < 2048; i += 256) Ws[i] = W[i];
  __syncthreads();
  int gid = blockIdx.x * 256 + threadIdx.x;
  int node = gid >> 5;
  int j = gid & 31;
  if (node >= n) return;
  const float* r = in + (size_t)node * 64;
  float acc = 0.0f;
#pragma unroll
  for (int k = 0; k < 64; k++) acc = fmaf(r[k], Ws[k * 32 + j], acc);
  out[(size_t)node * 32 + j] = acc;
}

// ---------------------------------------------------------------------------
// out = h @ (Wa [+ Wb]) + (ba [+ bb])   (64 -> 32); initializes d_out section.
// Layer-2 scatter kernels then atomically accumulate on top.
// ---------------------------------------------------------------------------
__global__ __launch_bounds__(256) void out_init(
    const float* __restrict__ h,
    const float* __restrict__ Wa,
    const float* __restrict__ Wb,   // may be nullptr
    const float* __restrict__ ba,
    const float* __restrict__ bb,   // may be nullptr
    float* __restrict__ out, int n) {
  __shared__ float Ws[64 * 32];
  __shared__ float bs[32];
  for (int i = threadIdx.x; i < 2048; i += 256)
    Ws[i] = Wa[i] + (Wb ? Wb[i] : 0.0f);
  if (threadIdx.x < 32)
    bs[threadIdx.x] = ba[threadIdx.x] + (bb ? bb[threadIdx.x] : 0.0f);
  __syncthreads();
  int gid = blockIdx.x * 256 + threadIdx.x;
  int node = gid >> 5;
  int j = gid & 31;
  if (node >= n) return;
  const float* r = h + (size_t)node * 64;
  float acc = bs[j];
#pragma unroll
  for (int k = 0; k < 64; k++) acc = fmaf(r[k], Ws[k * 32 + j], acc);
  out[(size_t)node * 32 + j] = acc;
}

static inline int nblk(long long threads) { return (int)((threads + 255) / 256); }

extern "C" void kernel_launch(void* const* d_in, const int* in_sizes, int n_in,
                              void* d_out, int out_size, void* d_ws, size_t ws_size,
                              hipStream_t stream) {
  const float* x_m = (const float*)d_in[0];
  const float* x_d = (const float*)d_in[1];
  const float* x_a = (const float*)d_in[2];
  const int* src_md = (const int*)d_in[3];
  const int* dst_md = (const int*)d_in[4];
  const float* ew_md = (const float*)d_in[5];
  const int* src_dm = (const int*)d_in[6];
  const int* dst_dm = (const int*)d_in[7];
  const float* ew_dm = (const float*)d_in[8];
  const int* src_ma = (const int*)d_in[9];
  const int* dst_ma = (const int*)d_in[10];
  const float* ew_ma = (const float*)d_in[11];
  const int* src_am = (const int*)d_in[12];
  const int* dst_am = (const int*)d_in[13];
  const float* ew_am = (const float*)d_in[14];
  const float* W1_rel = (const float*)d_in[15];
  const float* b1 = (const float*)d_in[16];
  const float* W1_root = (const float*)d_in[17];
  const float* W2_rel = (const float*)d_in[18];
  const float* b2 = (const float*)d_in[19];
  const float* W2_root = (const float*)d_in[20];

  const int E_md = in_sizes[3];
  const int E_dm = in_sizes[6];
  const int E_ma = in_sizes[9];
  const int E_am = in_sizes[12];

  // ---- workspace layout (floats) ----
  // Region A (layer-1 agg, zeroed):  agg_md | agg_dm | agg_ma | agg_am
  // Region B:                        h_m | h_d | h_a
  // y_* alias Region A (agg dead after h computed).
  float* ws = (float*)d_ws;
  float* agg_md = ws;
  float* agg_dm = agg_md + (size_t)N_D * 64;
  float* agg_ma = agg_dm + (size_t)N_M * 64;
  float* agg_am = agg_ma + (size_t)N_A * 64;
  float* h_m    = agg_am + (size_t)N_M * 64;
  float* h_d    = h_m + (size_t)N_M * 64;
  float* h_a    = h_d + (size_t)N_D * 64;

  float* y_md = agg_md;                       // N_M*32
  float* y_dm = y_md + (size_t)N_M * 32;      // N_D*32
  float* y_ma = y_dm + (size_t)N_D * 32;      // N_M*32
  float* y_am = y_ma + (size_t)N_M * 32;      // N_A*32

  size_t needFloats = ((size_t)N_D + N_M + N_A + N_M) * 64   // agg
                    + ((size_t)N_M + N_D + N_A) * 64;        // h
  if (ws_size < needFloats * sizeof(float)) return;  // fail loudly via bad output

  float* o_m = (float*)d_out;
  float* o_d = o_m + (size_t)N_M * 32;
  float* o_a = o_d + (size_t)N_D * 32;

  // ---- layer 1: zero agg, scatter, node update ----
  size_t aggBytes = ((size_t)N_D + N_M + N_A + N_M) * 64 * sizeof(float);
  hipMemsetAsync(ws, 0, aggBytes, stream);

  scatter_kernel<64><<<nblk((long long)E_md * 16), 256, 0, stream>>>(x_m, src_md, dst_md, ew_md, agg_md, E_md);
  scatter_kernel<64><<<nblk((long long)E_dm * 16), 256, 0, stream>>>(x_d, src_dm, dst_dm, ew_dm, agg_dm, E_dm);
  scatter_kernel<64><<<nblk((long long)E_ma * 16), 256, 0, stream>>>(x_m, src_ma, dst_ma, ew_ma, agg_ma, E_ma);
  scatter_kernel<64><<<nblk((long long)E_am * 16), 256, 0, stream>>>(x_a, src_am, dst_am, ew_am, agg_am, E_am);

  l1_node1<<<512, 256, 0, stream>>>(agg_md, x_d, W1_rel + 0 * 4096, b1 + 0 * 64, W1_root + 0 * 4096, h_d, N_D);
  l1_node_movie<<<512, 256, 0, stream>>>(agg_dm, agg_am, x_m, W1_rel, b1, W1_root, h_m, N_M);
  l1_node1<<<512, 256, 0, stream>>>(agg_ma, x_a, W1_rel + 2 * 4096, b1 + 2 * 64, W1_root + 2 * 4096, h_a, N_A);

  // ---- layer 2: pre-transform sources through W2_rel (scatter width 64->32) ----
  matmul_64x32<<<nblk((long long)N_M * 32), 256, 0, stream>>>(h_m, W2_rel + 0 * 2048, y_md, N_M);
  matmul_64x32<<<nblk((long long)N_D * 32), 256, 0, stream>>>(h_d, W2_rel + 1 * 2048, y_dm, N_D);
  matmul_64x32<<<nblk((long long)N_M * 32), 256, 0, stream>>>(h_m, W2_rel + 2 * 2048, y_ma, N_M);
  matmul_64x32<<<nblk((long long)N_A * 32), 256, 0, stream>>>(h_a, W2_rel + 3 * 2048, y_am, N_A);

  // ---- init outputs with root + bias terms ----
  out_init<<<nblk((long long)N_M * 32), 256, 0, stream>>>(h_m, W2_root + 1 * 2048, W2_root + 3 * 2048, b2 + 1 * 32, b2 + 3 * 32, o_m, N_M);
  out_init<<<nblk((long long)N_D * 32), 256, 0, stream>>>(h_d, W2_root + 0 * 2048, nullptr, b2 + 0 * 32, nullptr, o_d, N_D);
  out_init<<<nblk((long long)N_A * 32), 256, 0, stream>>>(h_a, W2_root + 2 * 2048, nullptr, b2 + 2 * 32, nullptr, o_a, N_A);

  // ---- layer 2 scatter: accumulate y over edges directly into d_out ----
  scatter_kernel<32><<<nblk((long long)E_md * 8), 256, 0, stream>>>(y_md, src_md, dst_md, ew_md, o_d, E_md);
  scatter_kernel<32><<<nblk((long long)E_dm * 8), 256, 0, stream>>>(y_dm, src_dm, dst_dm, ew_dm, o_m, E_dm);
  scatter_kernel<32><<<nblk((long long)E_ma * 8), 256, 0, stream>>>(y_ma, src_ma, dst_ma, ew_ma, o_a, E_ma);
  scatter_kernel<32><<<nblk((long long)E_am * 8), 256, 0, stream>>>(y_am, src_am, dst_am, ew_am, o_m, E_am);
}

// Round 2
// 2190.292 us; speedup vs baseline: 4.3078x; 4.3078x over previous
//
#include <hip/hip_runtime.h>

#define N_M 100000
#define N_D 30000
#define N_A 80000

// ===========================================================================
// CSR build: histogram -> scan (rowptr+cursor) -> reorder edges into
// (src, ew) 8-byte pairs sorted by destination. Rebuilt every call (inputs
// are re-poisoned each launch; no static caching allowed).
// ===========================================================================

__global__ __launch_bounds__(256) void hist_kernel(
    const int* __restrict__ dst, int nE, int* __restrict__ counts) {
  int e = blockIdx.x * 256 + threadIdx.x;
  if (e < nE) atomicAdd(&counts[dst[e]], 1);
}

struct ScanArgs { int N[4]; int cOff[4]; int rOff[4]; };

// 4 blocks, one per graph. Exclusive scan of counts -> rowptr, also writes
// cursor (= rowptr start) for the reorder pass. Wave-shuffle scan, 8 elem/thr.
__global__ __launch_bounds__(1024) void scan_kernel(
    const int* __restrict__ counts, int* __restrict__ rowptr,
    int* __restrict__ cursor, ScanArgs a) {
  int g = blockIdx.x;
  int N = a.N[g];
  const int* c = counts + a.cOff[g];
  int* r = rowptr + a.rOff[g];
  int* u = cursor + a.cOff[g];
  __shared__ int wsum[16];
  int lane = threadIdx.x & 63, wid = threadIdx.x >> 6;
  int running = 0;
  const int TILE = 1024 * 8;
  for (int base = 0; base < N; base += TILE) {
    int idx0 = base + threadIdx.x * 8;
    int v[8];
    int s = 0;
#pragma unroll
    for (int i = 0; i < 8; i++) {
      int idx = idx0 + i;
      int t = (idx < N) ? c[idx] : 0;
      v[i] = t; s += t;
    }
    int sc = s;  // inclusive wave scan
#pragma unroll
    for (int off = 1; off < 64; off <<= 1) {
      int t = __shfl_up(sc, off, 64);
      if (lane >= off) sc += t;
    }
    if (lane == 63) wsum[wid] = sc;
    __syncthreads();
    int wexcl = 0, tot = 0;
    for (int w = 0; w < 16; w++) { int t = wsum[w]; if (w < wid) wexcl += t; tot += t; }
    int p = running + wexcl + (sc - s);
#pragma unroll
    for (int i = 0; i < 8; i++) {
      int idx = idx0 + i;
      if (idx < N) { r[idx] = p; u[idx] = p; }
      p += v[i];
    }
    running += tot;
    __syncthreads();
  }
  if (threadIdx.x == 0) r[N] = running;
}

__global__ __launch_bounds__(256) void reorder_kernel(
    const int* __restrict__ src, const int* __restrict__ dst,
    const float* __restrict__ ew, int nE,
    int* __restrict__ cursor, int2* __restrict__ pairs) {
  int e = blockIdx.x * 256 + threadIdx.x;
  if (e >= nE) return;
  int d = dst[e];
  int p = atomicAdd(&cursor[d], 1);
  pairs[p] = make_int2(src[e], __float_as_int(ew[e]));
}

// ===========================================================================
// Layer 1 fused: gather-aggregate (in registers, lane=feature) + node linear.
//   h = relu(agg @ Wrel + b + x @ Wroot)
// One wave per node. agg row lives in registers, broadcast via per-wave LDS
// scratch for the matvec (wave-lockstep, no barrier needed).
// ===========================================================================
__global__ __launch_bounds__(256) void l1_gather1(
    const int* __restrict__ rowptr, const int2* __restrict__ pairs,
    const float* __restrict__ xsrc, const float* __restrict__ xroot,
    const float* __restrict__ Wrel, const float* __restrict__ bias,
    const float* __restrict__ Wroot, float* __restrict__ h, int n) {
  __shared__ float Wr[4096];
  __shared__ float Wt[4096];
  __shared__ float scr[4][128];
  for (int i = threadIdx.x * 4; i < 4096; i += 1024) {
    *(float4*)&Wr[i] = *(const float4*)&Wrel[i];
    *(float4*)&Wt[i] = *(const float4*)&Wroot[i];
  }
  __syncthreads();
  int lane = threadIdx.x & 63, wid = threadIdx.x >> 6;
  int wave = blockIdx.x * 4 + wid, nW = gridDim.x * 4;
  float bj = bias[lane];
  for (int node = wave; node < n; node += nW) {
    int s0 = rowptr[node], s1 = rowptr[node + 1];
    float acc = 0.f;
    int e = s0;
    for (; e + 4 <= s1; e += 4) {
      int2 p0 = pairs[e], p1 = pairs[e + 1], p2 = pairs[e + 2], p3 = pairs[e + 3];
      float v0 = xsrc[(size_t)p0.x * 64 + lane];
      float v1 = xsrc[(size_t)p1.x * 64 + lane];
      float v2 = xsrc[(size_t)p2.x * 64 + lane];
      float v3 = xsrc[(size_t)p3.x * 64 + lane];
      acc += __int_as_float(p0.y) * v0 + __int_as_float(p1.y) * v1
           + __int_as_float(p2.y) * v2 + __int_as_float(p3.y) * v3;
    }
    for (; e < s1; e++) {
      int2 p = pairs[e];
      acc += __int_as_float(p.y) * xsrc[(size_t)p.x * 64 + lane];
    }
    scr[wid][lane] = acc;
    scr[wid][64 + lane] = xroot[(size_t)node * 64 + lane];
    float o = bj;
#pragma unroll
    for (int k = 0; k < 64; k++) {
      o = fmaf(scr[wid][k], Wr[k * 64 + lane], o);
      o = fmaf(scr[wid][64 + k], Wt[k * 64 + lane], o);
    }
    h[(size_t)node * 64 + lane] = fmaxf(o, 0.f);
  }
}

// Movie variant: two incoming relations (dm=1, am=3), HeteroConv sum.
__global__ __launch_bounds__(256) void l1_gather2(
    const int* __restrict__ rp1, const int2* __restrict__ pr1, const float* __restrict__ xs1,
    const int* __restrict__ rp2, const int2* __restrict__ pr2, const float* __restrict__ xs2,
    const float* __restrict__ xroot,
    const float* __restrict__ Wrel1, const float* __restrict__ Wrel3,
    const float* __restrict__ b1a, const float* __restrict__ b1b,
    const float* __restrict__ Wroot1, const float* __restrict__ Wroot3,
    float* __restrict__ h, int n) {
  __shared__ float Wr1[4096];
  __shared__ float Wr3[4096];
  __shared__ float Wt[4096];
  __shared__ float scr[4][192];
  for (int i = threadIdx.x * 4; i < 4096; i += 1024) {
    *(float4*)&Wr1[i] = *(const float4*)&Wrel1[i];
    *(float4*)&Wr3[i] = *(const float4*)&Wrel3[i];
    float4 a = *(const float4*)&Wroot1[i];
    float4 b = *(const float4*)&Wroot3[i];
    *(float4*)&Wt[i] = make_float4(a.x + b.x, a.y + b.y, a.z + b.z, a.w + b.w);
  }
  __syncthreads();
  int lane = threadIdx.x & 63, wid = threadIdx.x >> 6;
  int wave = blockIdx.x * 4 + wid, nW = gridDim.x * 4;
  float bj = b1a[lane] + b1b[lane];
  for (int node = wave; node < n; node += nW) {
    float acc1 = 0.f, acc2 = 0.f;
    {
      int s0 = rp1[node], s1 = rp1[node + 1];
      int e = s0;
      for (; e + 4 <= s1; e += 4) {
        int2 p0 = pr1[e], p1 = pr1[e + 1], p2 = pr1[e + 2], p3 = pr1[e + 3];
        float v0 = xs1[(size_t)p0.x * 64 + lane];
        float v1 = xs1[(size_t)p1.x * 64 + lane];
        float v2 = xs1[(size_t)p2.x * 64 + lane];
        float v3 = xs1[(size_t)p3.x * 64 + lane];
        acc1 += __int_as_float(p0.y) * v0 + __int_as_float(p1.y) * v1
              + __int_as_float(p2.y) * v2 + __int_as_float(p3.y) * v3;
      }
      for (; e < s1; e++) {
        int2 p = pr1[e];
        acc1 += __int_as_float(p.y) * xs1[(size_t)p.x * 64 + lane];
      }
    }
    {
      int s0 = rp2[node], s1 = rp2[node + 1];
      int e = s0;
      for (; e + 4 <= s1; e += 4) {
        int2 p0 = pr2[e], p1 = pr2[e + 1], p2 = pr2[e + 2], p3 = pr2[e + 3];
        float v0 = xs2[(size_t)p0.x * 64 + lane];
        float v1 = xs2[(size_t)p1.x * 64 + lane];
        float v2 = xs2[(size_t)p2.x * 64 + lane];
        float v3 = xs2[(size_t)p3.x * 64 + lane];
        acc2 += __int_as_float(p0.y) * v0 + __int_as_float(p1.y) * v1
              + __int_as_float(p2.y) * v2 + __int_as_float(p3.y) * v3;
      }
      for (; e < s1; e++) {
        int2 p = pr2[e];
        acc2 += __int_as_float(p.y) * xs2[(size_t)p.x * 64 + lane];
      }
    }
    scr[wid][lane] = acc1;
    scr[wid][64 + lane] = acc2;
    scr[wid][128 + lane] = xroot[(size_t)node * 64 + lane];
    float o = bj;
#pragma unroll
    for (int k = 0; k < 64; k++) {
      o = fmaf(scr[wid][k], Wr1[k * 64 + lane], o);
      o = fmaf(scr[wid][64 + k], Wr3[k * 64 + lane], o);
      o = fmaf(scr[wid][128 + k], Wt[k * 64 + lane], o);
    }
    h[(size_t)node * 64 + lane] = fmaxf(o, 0.f);
  }
}

// ===========================================================================
// y = h @ W2_rel (64 -> 32): transform-before-gather for layer 2.
// ===========================================================================
__global__ __launch_bounds__(256) void matmul_64x32(
    const float* __restrict__ in, const float* __restrict__ W,
    float* __restrict__ out, int n) {
  __shared__ float Ws[2048];
  for (int i = threadIdx.x; i < 2048; i += 256) Ws[i] = W[i];
  __syncthreads();
  int gid = blockIdx.x * 256 + threadIdx.x;
  int node = gid >> 5, j = gid & 31;
  if (node >= n) return;
  const float* r = in + (size_t)node * 64;
  float acc = 0.f;
#pragma unroll
  for (int k = 0; k < 64; k++) acc = fmaf(r[k], Ws[k * 32 + j], acc);
  out[(size_t)node * 32 + j] = acc;
}

// ===========================================================================
// Layer 2 fused output: out = b + h @ Wroot + gather(y over edges).
// One wave per node; half-waves split edges, lanes<32 = out dims.
// Second relation optional (movie). No atomics, out written exactly once.
// ===========================================================================
__global__ __launch_bounds__(256) void l2_out(
    const int* __restrict__ rp1, const int2* __restrict__ pr1, const float* __restrict__ y1,
    const int* __restrict__ rp2, const int2* __restrict__ pr2, const float* __restrict__ y2,
    const float* __restrict__ h,
    const float* __restrict__ Wa, const float* __restrict__ Wb,
    const float* __restrict__ ba, const float* __restrict__ bb,
    float* __restrict__ out, int n) {
  __shared__ float Ws[2048];
  __shared__ float bs[32];
  __shared__ float hrow[4][64];
  for (int i = threadIdx.x; i < 2048; i += 256) Ws[i] = Wa[i] + (Wb ? Wb[i] : 0.f);
  if (threadIdx.x < 32) bs[threadIdx.x] = ba[threadIdx.x] + (bb ? bb[threadIdx.x] : 0.f);
  __syncthreads();
  int lane = threadIdx.x & 63, wid = threadIdx.x >> 6;
  int wave = blockIdx.x * 4 + wid, nW = gridDim.x * 4;
  int j = lane & 31, half = lane >> 5;
  for (int node = wave; node < n; node += nW) {
    hrow[wid][lane] = h[(size_t)node * 64 + lane];
    float acc = 0.f;
#pragma unroll
    for (int kk = 0; kk < 32; kk++) {
      int k = (half << 5) + kk;
      acc = fmaf(hrow[wid][k], Ws[k * 32 + j], acc);
    }
    {
      int s1 = rp1[node + 1];
      int e = rp1[node] + half;
      for (; e + 6 < s1; e += 8) {  // 4 edges per half in flight
        int2 p0 = pr1[e], p1 = pr1[e + 2], p2 = pr1[e + 4], p3 = pr1[e + 6];
        float a0 = y1[(size_t)p0.x * 32 + j];
        float a1 = y1[(size_t)p1.x * 32 + j];
        float a2 = y1[(size_t)p2.x * 32 + j];
        float a3 = y1[(size_t)p3.x * 32 + j];
        acc += __int_as_float(p0.y) * a0 + __int_as_float(p1.y) * a1
             + __int_as_float(p2.y) * a2 + __int_as_float(p3.y) * a3;
      }
      for (; e < s1; e += 2) {
        int2 p = pr1[e];
        acc += __int_as_float(p.y) * y1[(size_t)p.x * 32 + j];
      }
    }
    if (rp2) {
      int s1 = rp2[node + 1];
      int e = rp2[node] + half;
      for (; e + 6 < s1; e += 8) {
        int2 p0 = pr2[e], p1 = pr2[e + 2], p2 = pr2[e + 4], p3 = pr2[e + 6];
        float a0 = y2[(size_t)p0.x * 32 + j];
        float a1 = y2[(size_t)p1.x * 32 + j];
        float a2 = y2[(size_t)p2.x * 32 + j];
        float a3 = y2[(size_t)p3.x * 32 + j];
        acc += __int_as_float(p0.y) * a0 + __int_as_float(p1.y) * a1
             + __int_as_float(p2.y) * a2 + __int_as_float(p3.y) * a3;
      }
      for (; e < s1; e += 2) {
        int2 p = pr2[e];
        acc += __int_as_float(p.y) * y2[(size_t)p.x * 32 + j];
      }
    }
    float other = __shfl_xor(acc, 32);
    acc += other;
    if (lane < 32) out[(size_t)node * 32 + lane] = acc + bs[lane];
  }
}

static inline int nblk(long long threads) { return (int)((threads + 255) / 256); }

extern "C" void kernel_launch(void* const* d_in, const int* in_sizes, int n_in,
                              void* d_out, int out_size, void* d_ws, size_t ws_size,
                              hipStream_t stream) {
  const float* x_m = (const float*)d_in[0];
  const float* x_d = (const float*)d_in[1];
  const float* x_a = (const float*)d_in[2];
  const int* src_md = (const int*)d_in[3];
  const int* dst_md = (const int*)d_in[4];
  const float* ew_md = (const float*)d_in[5];
  const int* src_dm = (const int*)d_in[6];
  const int* dst_dm = (const int*)d_in[7];
  const float* ew_dm = (const float*)d_in[8];
  const int* src_ma = (const int*)d_in[9];
  const int* dst_ma = (const int*)d_in[10];
  const float* ew_ma = (const float*)d_in[11];
  const int* src_am = (const int*)d_in[12];
  const int* dst_am = (const int*)d_in[13];
  const float* ew_am = (const float*)d_in[14];
  const float* W1_rel = (const float*)d_in[15];
  const float* b1 = (const float*)d_in[16];
  const float* W1_root = (const float*)d_in[17];
  const float* W2_rel = (const float*)d_in[18];
  const float* b2 = (const float*)d_in[19];
  const float* W2_root = (const float*)d_in[20];

  const int E_md = in_sizes[3];
  const int E_dm = in_sizes[6];
  const int E_ma = in_sizes[9];
  const int E_am = in_sizes[12];
  const long long E_tot = (long long)E_md + E_dm + E_ma + E_am;

  // ---- workspace layout (4-byte units) ----
  // pairs (int2, E_tot) | counts/cursor (310000) | rowptr (310004) | h | y
  char* w = (char*)d_ws;
  int2* pairs = (int2*)w;                 w += (size_t)E_tot * 8;
  int* cursor = (int*)w;                  w += (size_t)310000 * 4;
  int* rowptr = (int*)w;                  w += (size_t)310004 * 4;
  float* h_m = (float*)w;                 w += (size_t)N_M * 64 * 4;
  float* h_d = (float*)w;                 w += (size_t)N_D * 64 * 4;
  float* h_a = (float*)w;                 w += (size_t)N_A * 64 * 4;
  float* y_md = (float*)w;                w += (size_t)N_M * 32 * 4;
  float* y_dm = (float*)w;                w += (size_t)N_D * 32 * 4;
  float* y_ma = (float*)w;                w += (size_t)N_M * 32 * 4;
  float* y_am = (float*)w;                w += (size_t)N_A * 32 * 4;
  if ((size_t)(w - (char*)d_ws) > ws_size) return;

  // per-graph offsets: order [md, dm, ma, am]; dst domains [N_D, N_M, N_A, N_M]
  int cO_md = 0, cO_dm = 30000, cO_ma = 130000, cO_am = 210000;
  int rO_md = 0, rO_dm = 30001, rO_ma = 130002, rO_am = 210003;
  long long pO_md = 0, pO_dm = E_md, pO_ma = (long long)E_md + E_dm,
            pO_am = (long long)E_md + E_dm + E_ma;

  float* o_m = (float*)d_out;
  float* o_d = o_m + (size_t)N_M * 32;
  float* o_a = o_d + (size_t)N_D * 32;

  // ---- CSR build ----
  hipMemsetAsync(cursor, 0, 310000 * 4, stream);  // counts alias cursor
  hist_kernel<<<nblk(E_md), 256, 0, stream>>>(dst_md, E_md, cursor + cO_md);
  hist_kernel<<<nblk(E_dm), 256, 0, stream>>>(dst_dm, E_dm, cursor + cO_dm);
  hist_kernel<<<nblk(E_ma), 256, 0, stream>>>(dst_ma, E_ma, cursor + cO_ma);
  hist_kernel<<<nblk(E_am), 256, 0, stream>>>(dst_am, E_am, cursor + cO_am);

  ScanArgs sa;
  sa.N[0] = N_D; sa.N[1] = N_M; sa.N[2] = N_A; sa.N[3] = N_M;
  sa.cOff[0] = cO_md; sa.cOff[1] = cO_dm; sa.cOff[2] = cO_ma; sa.cOff[3] = cO_am;
  sa.rOff[0] = rO_md; sa.rOff[1] = rO_dm; sa.rOff[2] = rO_ma; sa.rOff[3] = rO_am;
  scan_kernel<<<4, 1024, 0, stream>>>(cursor, rowptr, cursor, sa);

  reorder_kernel<<<nblk(E_md), 256, 0, stream>>>(src_md, dst_md, ew_md, E_md, cursor + cO_md, pairs + pO_md);
  reorder_kernel<<<nblk(E_dm), 256, 0, stream>>>(src_dm, dst_dm, ew_dm, E_dm, cursor + cO_dm, pairs + pO_dm);
  reorder_kernel<<<nblk(E_ma), 256, 0, stream>>>(src_ma, dst_ma, ew_ma, E_ma, cursor + cO_ma, pairs + pO_ma);
  reorder_kernel<<<nblk(E_am), 256, 0, stream>>>(src_am, dst_am, ew_am, E_am, cursor + cO_am, pairs + pO_am);

  // ---- layer 1 (fused gather + linear + relu) ----
  l1_gather1<<<2048, 256, 0, stream>>>(rowptr + rO_md, pairs + pO_md, x_m, x_d,
                                       W1_rel + 0 * 4096, b1 + 0 * 64, W1_root + 0 * 4096, h_d, N_D);
  l1_gather1<<<2048, 256, 0, stream>>>(rowptr + rO_ma, pairs + pO_ma, x_m, x_a,
                                       W1_rel + 2 * 4096, b1 + 2 * 64, W1_root + 2 * 4096, h_a, N_A);
  l1_gather2<<<2048, 256, 0, stream>>>(rowptr + rO_dm, pairs + pO_dm, x_d,
                                       rowptr + rO_am, pairs + pO_am, x_a, x_m,
                                       W1_rel + 1 * 4096, W1_rel + 3 * 4096,
                                       b1 + 1 * 64, b1 + 3 * 64,
                                       W1_root + 1 * 4096, W1_root + 3 * 4096, h_m, N_M);

  // ---- layer 2: pre-transform sources ----
  matmul_64x32<<<nblk((long long)N_M * 32), 256, 0, stream>>>(h_m, W2_rel + 0 * 2048, y_md, N_M);
  matmul_64x32<<<nblk((long long)N_D * 32), 256, 0, stream>>>(h_d, W2_rel + 1 * 2048, y_dm, N_D);
  matmul_64x32<<<nblk((long long)N_M * 32), 256, 0, stream>>>(h_m, W2_rel + 2 * 2048, y_ma, N_M);
  matmul_64x32<<<nblk((long long)N_A * 32), 256, 0, stream>>>(h_a, W2_rel + 3 * 2048, y_am, N_A);

  // ---- layer 2 fused output (root + bias + gather), no atomics ----
  l2_out<<<2048, 256, 0, stream>>>(rowptr + rO_md, pairs + pO_md, y_md,
                                   nullptr, nullptr, nullptr,
                                   h_d, W2_root + 0 * 2048, nullptr, b2 + 0 * 32, nullptr, o_d, N_D);
  l2_out<<<2048, 256, 0, stream>>>(rowptr + rO_ma, pairs + pO_ma, y_ma,
                                   nullptr, nullptr, nullptr,
                                   h_a, W2_root + 2 * 2048, nullptr, b2 + 2 * 32, nullptr, o_a, N_A);
  l2_out<<<2048, 256, 0, stream>>>(rowptr + rO_dm, pairs + pO_dm, y_dm,
                                   rowptr + rO_am, pairs + pO_am, y_am,
                                   h_m, W2_root + 1 * 2048, W2_root + 3 * 2048,
                                   b2 + 1 * 32, b2 + 3 * 32, o_m, N_M);
}

// Round 3
// 1909.734 us; speedup vs baseline: 4.9407x; 1.1469x over previous
//
#include <hip/hip_runtime.h>

#define N_M 100000
#define N_D 30000
#define N_A 80000

typedef unsigned int u32;
typedef unsigned short u16;

// ---- bf16 helpers (manual RTN) ----
__device__ __forceinline__ u16 f2bf(float f) {
  u32 u = __float_as_uint(f);
  u32 r = (u + 0x7FFFu + ((u >> 16) & 1u)) >> 16;
  return (u16)r;
}
__device__ __forceinline__ float bf2f(u16 b) {
  return __uint_as_float(((u32)b) << 16);
}
// packed edge: src in bits [31:15] (src < 131072), bf16(ew) sans sign in [14:0]
__device__ __forceinline__ u32 pack_edge(int src, float ew) {
  return ((u32)src << 15) | ((u32)f2bf(ew) & 0x7FFFu);
}
__device__ __forceinline__ float edge_w(u32 p) {
  return __uint_as_float((p & 0x7FFFu) << 16);
}

// ===========================================================================
// CSR build
// ===========================================================================
__global__ __launch_bounds__(256) void hist_kernel(
    const int* __restrict__ dst, int nE, int* __restrict__ counts) {
  int e = blockIdx.x * 256 + threadIdx.x;
  if (e < nE) atomicAdd(&counts[dst[e]], 1);
}

struct ScanArgs { int N[4]; int cOff[4]; int rOff[4]; };

__global__ __launch_bounds__(1024) void scan_kernel(
    const int* __restrict__ counts, int* __restrict__ rowptr,
    int* __restrict__ cursor, ScanArgs a) {
  int g = blockIdx.x;
  int N = a.N[g];
  const int* c = counts + a.cOff[g];
  int* r = rowptr + a.rOff[g];
  int* u = cursor + a.cOff[g];
  __shared__ int wsum[16];
  int lane = threadIdx.x & 63, wid = threadIdx.x >> 6;
  int running = 0;
  const int TILE = 1024 * 8;
  for (int base = 0; base < N; base += TILE) {
    int idx0 = base + threadIdx.x * 8;
    int v[8];
    int s = 0;
#pragma unroll
    for (int i = 0; i < 8; i++) {
      int idx = idx0 + i;
      int t = (idx < N) ? c[idx] : 0;
      v[i] = t; s += t;
    }
    int sc = s;
#pragma unroll
    for (int off = 1; off < 64; off <<= 1) {
      int t = __shfl_up(sc, off, 64);
      if (lane >= off) sc += t;
    }
    if (lane == 63) wsum[wid] = sc;
    __syncthreads();
    int wexcl = 0, tot = 0;
    for (int w = 0; w < 16; w++) { int t = wsum[w]; if (w < wid) wexcl += t; tot += t; }
    int p = running + wexcl + (sc - s);
#pragma unroll
    for (int i = 0; i < 8; i++) {
      int idx = idx0 + i;
      if (idx < N) { r[idx] = p; u[idx] = p; }
      p += v[i];
    }
    running += tot;
    __syncthreads();
  }
  if (threadIdx.x == 0) r[N] = running;
}

__global__ __launch_bounds__(256) void reorder_kernel(
    const int* __restrict__ src, const int* __restrict__ dst,
    const float* __restrict__ ew, int nE,
    int* __restrict__ cursor, u32* __restrict__ pairs) {
  int e = blockIdx.x * 256 + threadIdx.x;
  if (e >= nE) return;
  int d = dst[e];
  int p = atomicAdd(&cursor[d], 1);
  pairs[p] = pack_edge(src[e], ew[e]);
}

// ===========================================================================
// Layer-1 dense transforms: t = x @ W1_rel (bf16), r = x @ W1_root + b (bf16)
// Wave handles 4 nodes: W element loaded once per k, x rows via L1 broadcast.
// ===========================================================================
__global__ __launch_bounds__(256) void l1_tr_m(
    const float* __restrict__ x,
    const float* __restrict__ Wr0, const float* __restrict__ Wr2,
    const float* __restrict__ Wt1, const float* __restrict__ Wt3,
    const float* __restrict__ b1a, const float* __restrict__ b1b,
    u16* __restrict__ t0, u16* __restrict__ t2, u16* __restrict__ r, int n) {
  __shared__ float A[4096], B[4096], C[4096];
  for (int i = threadIdx.x * 4; i < 4096; i += 1024) {
    *(float4*)&A[i] = *(const float4*)&Wr0[i];
    *(float4*)&B[i] = *(const float4*)&Wr2[i];
    float4 p = *(const float4*)&Wt1[i], q = *(const float4*)&Wt3[i];
    *(float4*)&C[i] = make_float4(p.x + q.x, p.y + q.y, p.z + q.z, p.w + q.w);
  }
  __syncthreads();
  int lane = threadIdx.x & 63, wid = threadIdx.x >> 6;
  int wave = blockIdx.x * 4 + wid, nW = gridDim.x * 4;
  float bj = b1a[lane] + b1b[lane];
  for (int base = wave * 4; base < n; base += nW * 4) {
    int n0 = base, n1 = min(base + 1, n - 1), n2 = min(base + 2, n - 1), n3 = min(base + 3, n - 1);
    float o0a = 0, o0b = 0, o0c = bj, o1a = 0, o1b = 0, o1c = bj;
    float o2a = 0, o2b = 0, o2c = bj, o3a = 0, o3b = 0, o3c = bj;
#pragma unroll 4
    for (int k = 0; k < 64; k++) {
      float wa = A[k * 64 + lane], wb = B[k * 64 + lane], wc = C[k * 64 + lane];
      float x0 = x[(size_t)n0 * 64 + k], x1 = x[(size_t)n1 * 64 + k];
      float x2 = x[(size_t)n2 * 64 + k], x3 = x[(size_t)n3 * 64 + k];
      o0a = fmaf(x0, wa, o0a); o0b = fmaf(x0, wb, o0b); o0c = fmaf(x0, wc, o0c);
      o1a = fmaf(x1, wa, o1a); o1b = fmaf(x1, wb, o1b); o1c = fmaf(x1, wc, o1c);
      o2a = fmaf(x2, wa, o2a); o2b = fmaf(x2, wb, o2b); o2c = fmaf(x2, wc, o2c);
      o3a = fmaf(x3, wa, o3a); o3b = fmaf(x3, wb, o3b); o3c = fmaf(x3, wc, o3c);
    }
    t0[(size_t)n0 * 64 + lane] = f2bf(o0a); t2[(size_t)n0 * 64 + lane] = f2bf(o0b); r[(size_t)n0 * 64 + lane] = f2bf(o0c);
    if (base + 1 < n) { t0[(size_t)n1 * 64 + lane] = f2bf(o1a); t2[(size_t)n1 * 64 + lane] = f2bf(o1b); r[(size_t)n1 * 64 + lane] = f2bf(o1c); }
    if (base + 2 < n) { t0[(size_t)n2 * 64 + lane] = f2bf(o2a); t2[(size_t)n2 * 64 + lane] = f2bf(o2b); r[(size_t)n2 * 64 + lane] = f2bf(o2c); }
    if (base + 3 < n) { t0[(size_t)n3 * 64 + lane] = f2bf(o3a); t2[(size_t)n3 * 64 + lane] = f2bf(o3b); r[(size_t)n3 * 64 + lane] = f2bf(o3c); }
  }
}

__global__ __launch_bounds__(256) void l1_tr_s(
    const float* __restrict__ x,
    const float* __restrict__ Wrel, const float* __restrict__ Wroot,
    const float* __restrict__ bias,
    u16* __restrict__ t, u16* __restrict__ r, int n) {
  __shared__ float A[4096], C[4096];
  for (int i = threadIdx.x * 4; i < 4096; i += 1024) {
    *(float4*)&A[i] = *(const float4*)&Wrel[i];
    *(float4*)&C[i] = *(const float4*)&Wroot[i];
  }
  __syncthreads();
  int lane = threadIdx.x & 63, wid = threadIdx.x >> 6;
  int wave = blockIdx.x * 4 + wid, nW = gridDim.x * 4;
  float bj = bias[lane];
  for (int base = wave * 4; base < n; base += nW * 4) {
    int n0 = base, n1 = min(base + 1, n - 1), n2 = min(base + 2, n - 1), n3 = min(base + 3, n - 1);
    float o0a = 0, o0c = bj, o1a = 0, o1c = bj, o2a = 0, o2c = bj, o3a = 0, o3c = bj;
#pragma unroll 4
    for (int k = 0; k < 64; k++) {
      float wa = A[k * 64 + lane], wc = C[k * 64 + lane];
      float x0 = x[(size_t)n0 * 64 + k], x1 = x[(size_t)n1 * 64 + k];
      float x2 = x[(size_t)n2 * 64 + k], x3 = x[(size_t)n3 * 64 + k];
      o0a = fmaf(x0, wa, o0a); o0c = fmaf(x0, wc, o0c);
      o1a = fmaf(x1, wa, o1a); o1c = fmaf(x1, wc, o1c);
      o2a = fmaf(x2, wa, o2a); o2c = fmaf(x2, wc, o2c);
      o3a = fmaf(x3, wa, o3a); o3c = fmaf(x3, wc, o3c);
    }
    t[(size_t)n0 * 64 + lane] = f2bf(o0a); r[(size_t)n0 * 64 + lane] = f2bf(o0c);
    if (base + 1 < n) { t[(size_t)n1 * 64 + lane] = f2bf(o1a); r[(size_t)n1 * 64 + lane] = f2bf(o1c); }
    if (base + 2 < n) { t[(size_t)n2 * 64 + lane] = f2bf(o2a); r[(size_t)n2 * 64 + lane] = f2bf(o2c); }
    if (base + 3 < n) { t[(size_t)n3 * 64 + lane] = f2bf(o3a); r[(size_t)n3 * 64 + lane] = f2bf(o3c); }
  }
}

// ===========================================================================
// Fused: layer-1 gather (h in registers) + relu + layer-2 transform.
// Gather loop has no weight LDS -> high occupancy + 8-deep ILP.
// ===========================================================================
__device__ __forceinline__ float gather64(
    const int* __restrict__ rp, const u32* __restrict__ pr,
    const u16* __restrict__ tbl, int node, int lane) {
  int e = rp[node], s1 = rp[node + 1];
  float acc = 0.f;
  for (; e + 8 <= s1; e += 8) {
    u32 p0 = pr[e], p1 = pr[e + 1], p2 = pr[e + 2], p3 = pr[e + 3];
    u32 p4 = pr[e + 4], p5 = pr[e + 5], p6 = pr[e + 6], p7 = pr[e + 7];
    float v0 = bf2f(tbl[(size_t)(p0 >> 15) * 64 + lane]);
    float v1 = bf2f(tbl[(size_t)(p1 >> 15) * 64 + lane]);
    float v2 = bf2f(tbl[(size_t)(p2 >> 15) * 64 + lane]);
    float v3 = bf2f(tbl[(size_t)(p3 >> 15) * 64 + lane]);
    float v4 = bf2f(tbl[(size_t)(p4 >> 15) * 64 + lane]);
    float v5 = bf2f(tbl[(size_t)(p5 >> 15) * 64 + lane]);
    float v6 = bf2f(tbl[(size_t)(p6 >> 15) * 64 + lane]);
    float v7 = bf2f(tbl[(size_t)(p7 >> 15) * 64 + lane]);
    acc += edge_w(p0) * v0 + edge_w(p1) * v1 + edge_w(p2) * v2 + edge_w(p3) * v3
         + edge_w(p4) * v4 + edge_w(p5) * v5 + edge_w(p6) * v6 + edge_w(p7) * v7;
  }
  for (; e < s1; e++) {
    u32 p = pr[e];
    acc += edge_w(p) * bf2f(tbl[(size_t)(p >> 15) * 64 + lane]);
  }
  return acc;
}

__global__ __launch_bounds__(256) void fused_s(
    const int* __restrict__ rp, const u32* __restrict__ pr,
    const u16* __restrict__ tbl, const u16* __restrict__ r1,
    const float* __restrict__ W2r, const float* __restrict__ W2t,
    const float* __restrict__ b2s,
    u16* __restrict__ y, u16* __restrict__ r2, int n) {
  __shared__ float Wy[2048], Wt[2048];
  __shared__ float bs[32];
  __shared__ float scr[4][64];
  for (int i = threadIdx.x * 4; i < 2048; i += 1024) {
    *(float4*)&Wy[i] = *(const float4*)&W2r[i];
    *(float4*)&Wt[i] = *(const float4*)&W2t[i];
  }
  if (threadIdx.x < 32) bs[threadIdx.x] = b2s[threadIdx.x];
  __syncthreads();
  int lane = threadIdx.x & 63, wid = threadIdx.x >> 6;
  int wave = blockIdx.x * 4 + wid, nW = gridDim.x * 4;
  int j = lane & 31, half = lane >> 5;
  for (int node = wave; node < n; node += nW) {
    float acc = gather64(rp, pr, tbl, node, lane);
    float hv = fmaxf(acc + bf2f(r1[(size_t)node * 64 + lane]), 0.f);
    scr[wid][lane] = hv;
    float oy = 0.f, ot = 0.f;
#pragma unroll
    for (int kk = 0; kk < 32; kk++) {
      int k = (half << 5) + kk;
      float s = scr[wid][k];
      oy = fmaf(s, Wy[k * 32 + j], oy);
      ot = fmaf(s, Wt[k * 32 + j], ot);
    }
    oy += __shfl_xor(oy, 32);
    ot += __shfl_xor(ot, 32);
    if (lane < 32) {
      y[(size_t)node * 32 + lane] = f2bf(oy);
      r2[(size_t)node * 32 + lane] = f2bf(ot + bs[lane]);
    }
  }
}

__global__ __launch_bounds__(256) void fused_m(
    const int* __restrict__ rp1, const u32* __restrict__ pr1, const u16* __restrict__ tbl1,
    const int* __restrict__ rp2, const u32* __restrict__ pr2, const u16* __restrict__ tbl2,
    const u16* __restrict__ r1,
    const float* __restrict__ W2r0, const float* __restrict__ W2r2,
    const float* __restrict__ W2t1, const float* __restrict__ W2t3,
    const float* __restrict__ b2a, const float* __restrict__ b2b,
    u16* __restrict__ y0, u16* __restrict__ y2, u16* __restrict__ r2, int n) {
  __shared__ float Wy0[2048], Wy2[2048], Wt[2048];
  __shared__ float bs[32];
  __shared__ float scr[4][64];
  for (int i = threadIdx.x * 4; i < 2048; i += 1024) {
    *(float4*)&Wy0[i] = *(const float4*)&W2r0[i];
    *(float4*)&Wy2[i] = *(const float4*)&W2r2[i];
    float4 p = *(const float4*)&W2t1[i], q = *(const float4*)&W2t3[i];
    *(float4*)&Wt[i] = make_float4(p.x + q.x, p.y + q.y, p.z + q.z, p.w + q.w);
  }
  if (threadIdx.x < 32) bs[threadIdx.x] = b2a[threadIdx.x] + b2b[threadIdx.x];
  __syncthreads();
  int lane = threadIdx.x & 63, wid = threadIdx.x >> 6;
  int wave = blockIdx.x * 4 + wid, nW = gridDim.x * 4;
  int j = lane & 31, half = lane >> 5;
  for (int node = wave; node < n; node += nW) {
    float acc = gather64(rp1, pr1, tbl1, node, lane)
              + gather64(rp2, pr2, tbl2, node, lane);
    float hv = fmaxf(acc + bf2f(r1[(size_t)node * 64 + lane]), 0.f);
    scr[wid][lane] = hv;
    float o0 = 0.f, o2 = 0.f, ot = 0.f;
#pragma unroll
    for (int kk = 0; kk < 32; kk++) {
      int k = (half << 5) + kk;
      float s = scr[wid][k];
      o0 = fmaf(s, Wy0[k * 32 + j], o0);
      o2 = fmaf(s, Wy2[k * 32 + j], o2);
      ot = fmaf(s, Wt[k * 32 + j], ot);
    }
    o0 += __shfl_xor(o0, 32);
    o2 += __shfl_xor(o2, 32);
    ot += __shfl_xor(ot, 32);
    if (lane < 32) {
      y0[(size_t)node * 32 + lane] = f2bf(o0);
      y2[(size_t)node * 32 + lane] = f2bf(o2);
      r2[(size_t)node * 32 + lane] = f2bf(ot + bs[lane]);
    }
  }
}

// ===========================================================================
// Layer-2 gather: out = sum_e w*y[src] + r2. Width 32, half-wave edge split.
// ===========================================================================
__global__ __launch_bounds__(256) void out_s(
    const int* __restrict__ rp, const u32* __restrict__ pr,
    const u16* __restrict__ y, const u16* __restrict__ r2,
    float* __restrict__ out, int n) {
  int lane = threadIdx.x & 63, wid = threadIdx.x >> 6;
  int wave = blockIdx.x * 4 + wid, nW = gridDim.x * 4;
  int j = lane & 31, half = lane >> 5;
  for (int node = wave; node < n; node += nW) {
    float acc = 0.f;
    int s1 = rp[node + 1];
    int e = rp[node] + half;
    for (; e + 6 < s1; e += 8) {
      u32 p0 = pr[e], p1 = pr[e + 2], p2 = pr[e + 4], p3 = pr[e + 6];
      acc += edge_w(p0) * bf2f(y[(size_t)(p0 >> 15) * 32 + j])
           + edge_w(p1) * bf2f(y[(size_t)(p1 >> 15) * 32 + j])
           + edge_w(p2) * bf2f(y[(size_t)(p2 >> 15) * 32 + j])
           + edge_w(p3) * bf2f(y[(size_t)(p3 >> 15) * 32 + j]);
    }
    for (; e < s1; e += 2) {
      u32 p = pr[e];
      acc += edge_w(p) * bf2f(y[(size_t)(p >> 15) * 32 + j]);
    }
    acc += __shfl_xor(acc, 32);
    if (lane < 32) out[(size_t)node * 32 + lane] = acc + bf2f(r2[(size_t)node * 32 + lane]);
  }
}

__global__ __launch_bounds__(256) void out_m(
    const int* __restrict__ rp1, const u32* __restrict__ pr1, const u16* __restrict__ y1,
    const int* __restrict__ rp2, const u32* __restrict__ pr2, const u16* __restrict__ y2,
    const u16* __restrict__ r2,
    float* __restrict__ out, int n) {
  int lane = threadIdx.x & 63, wid = threadIdx.x >> 6;
  int wave = blockIdx.x * 4 + wid, nW = gridDim.x * 4;
  int j = lane & 31, half = lane >> 5;
  for (int node = wave; node < n; node += nW) {
    float acc = 0.f;
    {
      int s1 = rp1[node + 1];
      int e = rp1[node] + half;
      for (; e + 6 < s1; e += 8) {
        u32 p0 = pr1[e], p1 = pr1[e + 2], p2 = pr1[e + 4], p3 = pr1[e + 6];
        acc += edge_w(p0) * bf2f(y1[(size_t)(p0 >> 15) * 32 + j])
             + edge_w(p1) * bf2f(y1[(size_t)(p1 >> 15) * 32 + j])
             + edge_w(p2) * bf2f(y1[(size_t)(p2 >> 15) * 32 + j])
             + edge_w(p3) * bf2f(y1[(size_t)(p3 >> 15) * 32 + j]);
      }
      for (; e < s1; e += 2) {
        u32 p = pr1[e];
        acc += edge_w(p) * bf2f(y1[(size_t)(p >> 15) * 32 + j]);
      }
    }
    {
      int s1 = rp2[node + 1];
      int e = rp2[node] + half;
      for (; e + 6 < s1; e += 8) {
        u32 p0 = pr2[e], p1 = pr2[e + 2], p2 = pr2[e + 4], p3 = pr2[e + 6];
        acc += edge_w(p0) * bf2f(y2[(size_t)(p0 >> 15) * 32 + j])
             + edge_w(p1) * bf2f(y2[(size_t)(p1 >> 15) * 32 + j])
             + edge_w(p2) * bf2f(y2[(size_t)(p2 >> 15) * 32 + j])
             + edge_w(p3) * bf2f(y2[(size_t)(p3 >> 15) * 32 + j]);
      }
      for (; e < s1; e += 2) {
        u32 p = pr2[e];
        acc += edge_w(p) * bf2f(y2[(size_t)(p >> 15) * 32 + j]);
      }
    }
    acc += __shfl_xor(acc, 32);
    if (lane < 32) out[(size_t)node * 32 + lane] = acc + bf2f(r2[(size_t)node * 32 + lane]);
  }
}

static inline int nblk(long long threads) { return (int)((threads + 255) / 256); }

extern "C" void kernel_launch(void* const* d_in, const int* in_sizes, int n_in,
                              void* d_out, int out_size, void* d_ws, size_t ws_size,
                              hipStream_t stream) {
  const float* x_m = (const float*)d_in[0];
  const float* x_d = (const float*)d_in[1];
  const float* x_a = (const float*)d_in[2];
  const int* src_md = (const int*)d_in[3];
  const int* dst_md = (const int*)d_in[4];
  const float* ew_md = (const float*)d_in[5];
  const int* src_dm = (const int*)d_in[6];
  const int* dst_dm = (const int*)d_in[7];
  const float* ew_dm = (const float*)d_in[8];
  const int* src_ma = (const int*)d_in[9];
  const int* dst_ma = (const int*)d_in[10];
  const float* ew_ma = (const float*)d_in[11];
  const int* src_am = (const int*)d_in[12];
  const int* dst_am = (const int*)d_in[13];
  const float* ew_am = (const float*)d_in[14];
  const float* W1_rel = (const float*)d_in[15];
  const float* b1 = (const float*)d_in[16];
  const float* W1_root = (const float*)d_in[17];
  const float* W2_rel = (const float*)d_in[18];
  const float* b2 = (const float*)d_in[19];
  const float* W2_root = (const float*)d_in[20];

  const int E_md = in_sizes[3];
  const int E_dm = in_sizes[6];
  const int E_ma = in_sizes[9];
  const int E_am = in_sizes[12];
  const long long E_tot = (long long)E_md + E_dm + E_ma + E_am;

  // ---- workspace layout ----
  char* w = (char*)d_ws;
  u32* pairs = (u32*)w;     w += (size_t)E_tot * 4;
  int* cursor = (int*)w;    w += (size_t)310000 * 4;
  int* rowptr = (int*)w;    w += (size_t)310004 * 4;
  u16* t_md = (u16*)w;      w += (size_t)N_M * 64 * 2;
  u16* t_dm = (u16*)w;      w += (size_t)N_D * 64 * 2;
  u16* t_ma = (u16*)w;      w += (size_t)N_M * 64 * 2;
  u16* t_am = (u16*)w;      w += (size_t)N_A * 64 * 2;
  u16* r_m  = (u16*)w;      w += (size_t)N_M * 64 * 2;
  u16* r_d  = (u16*)w;      w += (size_t)N_D * 64 * 2;
  u16* r_a  = (u16*)w;      w += (size_t)N_A * 64 * 2;
  u16* y_md = (u16*)w;      w += (size_t)N_M * 32 * 2;
  u16* y_dm = (u16*)w;      w += (size_t)N_D * 32 * 2;
  u16* y_ma = (u16*)w;      w += (size_t)N_M * 32 * 2;
  u16* y_am = (u16*)w;      w += (size_t)N_A * 32 * 2;
  u16* r2_m = (u16*)w;      w += (size_t)N_M * 32 * 2;
  u16* r2_d = (u16*)w;      w += (size_t)N_D * 32 * 2;
  u16* r2_a = (u16*)w;      w += (size_t)N_A * 32 * 2;
  if ((size_t)(w - (char*)d_ws) > ws_size) return;

  int cO_md = 0, cO_dm = 30000, cO_ma = 130000, cO_am = 210000;
  int rO_md = 0, rO_dm = 30001, rO_ma = 130002, rO_am = 210003;
  long long pO_md = 0, pO_dm = E_md, pO_ma = (long long)E_md + E_dm,
            pO_am = (long long)E_md + E_dm + E_ma;

  float* o_m = (float*)d_out;
  float* o_d = o_m + (size_t)N_M * 32;
  float* o_a = o_d + (size_t)N_D * 32;

  // ---- CSR build ----
  hipMemsetAsync(cursor, 0, 310000 * 4, stream);
  hist_kernel<<<nblk(E_md), 256, 0, stream>>>(dst_md, E_md, cursor + cO_md);
  hist_kernel<<<nblk(E_dm), 256, 0, stream>>>(dst_dm, E_dm, cursor + cO_dm);
  hist_kernel<<<nblk(E_ma), 256, 0, stream>>>(dst_ma, E_ma, cursor + cO_ma);
  hist_kernel<<<nblk(E_am), 256, 0, stream>>>(dst_am, E_am, cursor + cO_am);

  ScanArgs sa;
  sa.N[0] = N_D; sa.N[1] = N_M; sa.N[2] = N_A; sa.N[3] = N_M;
  sa.cOff[0] = cO_md; sa.cOff[1] = cO_dm; sa.cOff[2] = cO_ma; sa.cOff[3] = cO_am;
  sa.rOff[0] = rO_md; sa.rOff[1] = rO_dm; sa.rOff[2] = rO_ma; sa.rOff[3] = rO_am;
  scan_kernel<<<4, 1024, 0, stream>>>(cursor, rowptr, cursor, sa);

  reorder_kernel<<<nblk(E_md), 256, 0, stream>>>(src_md, dst_md, ew_md, E_md, cursor + cO_md, pairs + pO_md);
  reorder_kernel<<<nblk(E_dm), 256, 0, stream>>>(src_dm, dst_dm, ew_dm, E_dm, cursor + cO_dm, pairs + pO_dm);
  reorder_kernel<<<nblk(E_ma), 256, 0, stream>>>(src_ma, dst_ma, ew_ma, E_ma, cursor + cO_ma, pairs + pO_ma);
  reorder_kernel<<<nblk(E_am), 256, 0, stream>>>(src_am, dst_am, ew_am, E_am, cursor + cO_am, pairs + pO_am);

  // ---- layer-1 dense transforms ----
  l1_tr_m<<<768, 256, 0, stream>>>(x_m, W1_rel + 0 * 4096, W1_rel + 2 * 4096,
                                   W1_root + 1 * 4096, W1_root + 3 * 4096,
                                   b1 + 1 * 64, b1 + 3 * 64, t_md, t_ma, r_m, N_M);
  l1_tr_s<<<512, 256, 0, stream>>>(x_d, W1_rel + 1 * 4096, W1_root + 0 * 4096,
                                   b1 + 0 * 64, t_dm, r_d, N_D);
  l1_tr_s<<<512, 256, 0, stream>>>(x_a, W1_rel + 3 * 4096, W1_root + 2 * 4096,
                                   b1 + 2 * 64, t_am, r_a, N_A);

  // ---- fused layer-1 gather + relu + layer-2 transform ----
  fused_s<<<2048, 256, 0, stream>>>(rowptr + rO_md, pairs + pO_md, t_md, r_d,
                                    W2_rel + 1 * 2048, W2_root + 0 * 2048, b2 + 0 * 32,
                                    y_dm, r2_d, N_D);
  fused_s<<<2048, 256, 0, stream>>>(rowptr + rO_ma, pairs + pO_ma, t_ma, r_a,
                                    W2_rel + 3 * 2048, W2_root + 2 * 2048, b2 + 2 * 32,
                                    y_am, r2_a, N_A);
  fused_m<<<2048, 256, 0, stream>>>(rowptr + rO_dm, pairs + pO_dm, t_dm,
                                    rowptr + rO_am, pairs + pO_am, t_am, r_m,
                                    W2_rel + 0 * 2048, W2_rel + 2 * 2048,
                                    W2_root + 1 * 2048, W2_root + 3 * 2048,
                                    b2 + 1 * 32, b2 + 3 * 32,
                                    y_md, y_ma, r2_m, N_M);

  // ---- layer-2 gather -> outputs ----
  out_s<<<1024, 256, 0, stream>>>(rowptr + rO_md, pairs + pO_md, y_md, r2_d, o_d, N_D);
  out_s<<<2048, 256, 0, stream>>>(rowptr + rO_ma, pairs + pO_ma, y_ma, r2_a, o_a, N_A);
  out_m<<<2048, 256, 0, stream>>>(rowptr + rO_dm, pairs + pO_dm, y_dm,
                                  rowptr + rO_am, pairs + pO_am, y_am,
                                  r2_m, o_m, N_M);
}